// Round 9
// baseline (846.184 us; speedup 1.0000x reference)
//
#include <hip/hip_runtime.h>
#include <hip/hip_bf16.h>
#include <math.h>

// ---------- types ----------
typedef __bf16 bf16x8 __attribute__((ext_vector_type(8)));
typedef float f32x4 __attribute__((ext_vector_type(4)));
struct __align__(16) US8 { unsigned short v[8]; };

typedef __attribute__((address_space(1))) const unsigned short GUS;
typedef __attribute__((address_space(3))) unsigned short LUS;
static __device__ __forceinline__ void gload16(const unsigned short* g, unsigned short* l) {
    // stages 16B per lane: LDS dest = wave-uniform base + lane*16
    __builtin_amdgcn_global_load_lds((GUS*)g, (LUS*)l, 16, 0, 0);
}

static __device__ __forceinline__ unsigned short f2bf(float f) {
    unsigned int u = __float_as_uint(f);
    unsigned int r = (u + 0x7fffu + ((u >> 16) & 1u)) >> 16;  // RNE
    return (unsigned short)r;
}
static __device__ __forceinline__ float bf2f(unsigned short u) {
    return __uint_as_float(((unsigned int)u) << 16);
}

// ---------- fp32 -> bf16 bulk convert (8 elems/thread) ----------
__global__ void cvt_bf16_kernel(const float* __restrict__ in, unsigned short* __restrict__ outb,
                                int total8) {
    int i = blockIdx.x * 256 + threadIdx.x;
    if (i < total8) {
        const float4* p = (const float4*)(in + (size_t)i * 8);
        float4 a = p[0], b = p[1];
        US8 o;
        o.v[0] = f2bf(a.x); o.v[1] = f2bf(a.y); o.v[2] = f2bf(a.z); o.v[3] = f2bf(a.w);
        o.v[4] = f2bf(b.x); o.v[5] = f2bf(b.y); o.v[6] = f2bf(b.z); o.v[7] = f2bf(b.w);
        *(US8*)(outb + (size_t)i * 8) = o;
    }
}

// ---------- init: deg=1 (self-loop), cnt=0, cursor=0 ----------
__global__ void init_kernel(float* deg, int* cnt, int* cursor, int M) {
    int i = blockIdx.x * 256 + threadIdx.x;
    if (i < M) { deg[i] = 1.0f; cnt[i] = 0; cursor[i] = 0; }
}
// ---------- per-edge: degree accumulate + in-degree count ----------
__global__ void deg_cnt_kernel(const int* __restrict__ ei, const float* __restrict__ ew,
                               float* deg, int* cnt, int E) {
    int e = blockIdx.x * 256 + threadIdx.x;
    if (e < E) {
        int c = ei[E + e];
        atomicAdd(&deg[c], ew[e]);
        atomicAdd(&cnt[c], 1);
    }
}
__global__ void dinv_kernel(const float* __restrict__ deg, float* dinv, int M) {
    int i = blockIdx.x * 256 + threadIdx.x;
    if (i < M) dinv[i] = rsqrtf(deg[i]);  // deg >= 1 always
}

// ---------- CSR build: chunk sums -> scan partials -> rowptr -> fill ----------
__global__ void chunk_sum_kernel(const int* __restrict__ cnt, int* partial, int M) {
    __shared__ int sd[256];
    int t = threadIdx.x;
    int i = blockIdx.x * 256 + t;
    sd[t] = (i < M) ? cnt[i] : 0;
    __syncthreads();
    for (int s = 128; s > 0; s >>= 1) {
        if (t < s) sd[t] += sd[t + s];
        __syncthreads();
    }
    if (t == 0) partial[blockIdx.x] = sd[0];
}
// single block, 512 threads, NB <= 512; partial becomes EXCLUSIVE scan
__global__ void scan_partial_kernel(int* partial, int NB) {
    __shared__ int sd[512];
    int t = threadIdx.x;
    int v = (t < NB) ? partial[t] : 0;
    sd[t] = v;
    __syncthreads();
    for (int o = 1; o < 512; o <<= 1) {
        int add = (t >= o) ? sd[t - o] : 0;
        __syncthreads();
        sd[t] += add;
        __syncthreads();
    }
    if (t < NB) partial[t] = sd[t] - v;  // exclusive
}
__global__ void rowptr_kernel(const int* __restrict__ cnt, const int* __restrict__ partial,
                              int* rowptr, int M, int E) {
    __shared__ int sd[256];
    int t = threadIdx.x;
    int i = blockIdx.x * 256 + t;
    int v = (i < M) ? cnt[i] : 0;
    sd[t] = v;
    __syncthreads();
    for (int o = 1; o < 256; o <<= 1) {
        int add = (t >= o) ? sd[t - o] : 0;
        __syncthreads();
        sd[t] += add;
        __syncthreads();
    }
    if (i < M) rowptr[i] = partial[blockIdx.x] + sd[t] - v;  // exclusive overall
    if (i == M - 1) rowptr[M] = E;
}
__global__ void csr_fill_kernel(const int* __restrict__ ei, const float* __restrict__ ew,
                                const float* __restrict__ dinv, const int* __restrict__ rowptr,
                                int* cursor, int* src, float* cf, int E) {
    int e = blockIdx.x * 256 + threadIdx.x;
    if (e < E) {
        int r = ei[e], c = ei[E + e];
        int k = atomicAdd(&cursor[c], 1);
        int pos = rowptr[c] + k;
        src[pos] = r;
        cf[pos] = dinv[r] * ew[e] * dinv[c];
    }
}

// ---------- W (512x512 row-major k,n) -> BT bf16 (n,k) ----------
__global__ void transpose_cvt_kernel(const float* __restrict__ W, unsigned short* __restrict__ BT) {
    int idx = blockIdx.x * 256 + threadIdx.x;  // 512*512
    int n = idx >> 9, k = idx & 511;
    BT[idx] = f2bf(W[k * 512 + n]);
}

// ---------- FUSED layer: gather -> GEMM -> epilogue, one block per 64 rows ----------
// 512 threads = 8 waves, BM=64 x BN=512.
// Phase 0: prestage B K-slices 0,1 (global_load_lds, fly during gather).
// Phase 1 (gather): wave w aggregates rows m0+w*8..+8 directly into LDS A-tile
//   (bf16, chunk swizzle c' = c ^ (m&7) so MFMA ds_read_b128 is 2-way = free).
// Phase 2 (K-loop): 16 iters, dbuf B staging, ONE barrier/iter; A read from LDS.
// Phase 3: bias+relu+rownorm+residual, bf16 store.
__global__ __launch_bounds__(512) void fused_layer_kernel(
    const unsigned short* __restrict__ xb,  // [M,512] bf16 layer input
    const int* __restrict__ rowptr,         // [M+1]
    const int* __restrict__ src,            // [E]
    const float* __restrict__ cf,           // [E]
    const float* __restrict__ dinv,         // [M]
    const unsigned short* __restrict__ BT,  // [512,512] bf16, n-major
    const float* __restrict__ bias,         // [512]
    unsigned short* __restrict__ outp,      // [M,512] bf16
    int M) {
    __shared__ __align__(16) unsigned short As[64 * 512];      // 64 KB full A tile
    __shared__ __align__(16) unsigned short Bs[2][512 * 32];   // 2 x 32 KB
    __shared__ float red[8 * 64];
    __shared__ float invn[64];

    const int tid  = threadIdx.x;
    const int m0   = blockIdx.x * 64;
    const int wave = tid >> 6;
    const int lane = tid & 63;
    const int q    = lane >> 4;   // 0..3
    const int r    = lane & 15;

    auto stageB = [&](int ks, int buf) {
        const int k0 = ks * 32;
        unsigned short* Bb = &Bs[buf][0];
        #pragma unroll
        for (int j = 0; j < 4; j++) {
            int c0 = j * 512 + wave * 64;   // wave-uniform chunk base
            int c  = c0 + lane;
            int n = c >> 2, kl = c & 3;
            int kc = kl ^ ((n + (n >> 2)) & 3);
            gload16(BT + (((size_t)n) << 9) + k0 + kc * 8, Bb + c0 * 8);
        }
    };

    // ---- phase 0: prestage B slices 0,1 ----
    stageB(0, 0);
    stageB(1, 1);

    // ---- phase 1: gather 8 rows per wave into LDS A tile ----
    for (int i = 0; i < 8; i++) {
        int m = wave * 8 + i;
        int gm = m0 + m;
        float a[8];
        if (gm < M) {
            float d = dinv[gm];
            float s = d * d;
            US8 v = *(const US8*)(xb + ((size_t)gm << 9) + lane * 8);
            #pragma unroll
            for (int t = 0; t < 8; t++) a[t] = s * bf2f(v.v[t]);
            int j = rowptr[gm], jend = rowptr[gm + 1];
            if (j < jend) {
                US8 u = *(const US8*)(xb + ((size_t)src[j] << 9) + lane * 8);
                float cv = cf[j];
                while (j < jend) {
                    int jn = j + 1;
                    US8 un; float cn = 0.f;
                    if (jn < jend) {  // prefetch next neighbor row
                        cn = cf[jn];
                        un = *(const US8*)(xb + ((size_t)src[jn] << 9) + lane * 8);
                    }
                    #pragma unroll
                    for (int t = 0; t < 8; t++) a[t] += cv * bf2f(u.v[t]);
                    u = un; cv = cn; j = jn;
                }
            }
        } else {
            #pragma unroll
            for (int t = 0; t < 8; t++) a[t] = 0.f;
        }
        US8 o;
        #pragma unroll
        for (int t = 0; t < 8; t++) o.v[t] = f2bf(a[t]);
        *(US8*)&As[(m << 9) + ((lane ^ (m & 7)) << 3)] = o;  // swizzled chunk
    }

    // ---- phase 2: K-loop (A from LDS, B dbuf-staged) ----
    f32x4 acc[4][4];
    #pragma unroll
    for (int mt = 0; mt < 4; mt++)
        #pragma unroll
        for (int nt = 0; nt < 4; nt++) acc[mt][nt] = (f32x4){0.f, 0.f, 0.f, 0.f};

    const int frB = (r + (r >> 2)) & 3;   // B swizzle term (per-lane constant)
    const int frA = r & 7;                // A swizzle term

    for (int ks = 0; ks < 16; ks++) {
        __syncthreads();  // drains staged B for this slice; frees other buffer
        if (ks >= 1 && ks + 1 < 16) stageB(ks + 1, (ks + 1) & 1);

        const int cur = ks & 1;
        bf16x8 af[4];
        #pragma unroll
        for (int mt = 0; mt < 4; mt++)
            af[mt] = __builtin_bit_cast(bf16x8,
                *(const US8*)&As[((mt * 16 + r) << 9) + (((ks * 4 + q) ^ frA) << 3)]);
        #pragma unroll
        for (int nt = 0; nt < 4; nt++) {
            bf16x8 bfr = __builtin_bit_cast(bf16x8,
                *(const US8*)&Bs[cur][((wave * 64 + nt * 16 + r) << 5) + ((q ^ frB) << 3)]);
            #pragma unroll
            for (int mt = 0; mt < 4; mt++)
                acc[mt][nt] = __builtin_amdgcn_mfma_f32_16x16x32_bf16(af[mt], bfr, acc[mt][nt], 0, 0, 0);
        }
    }

    // ---- phase 3: bias + relu, row-norm, residual, bf16 store ----
    float bs[4];
    #pragma unroll
    for (int nt = 0; nt < 4; nt++) bs[nt] = bias[wave * 64 + nt * 16 + r];

    float ss[4][4];
    #pragma unroll
    for (int mt = 0; mt < 4; mt++) {
        #pragma unroll
        for (int reg = 0; reg < 4; reg++) {
            float s = 0.f;
            #pragma unroll
            for (int nt = 0; nt < 4; nt++) {
                float t = fmaxf(acc[mt][nt][reg] + bs[nt], 0.f);
                acc[mt][nt][reg] = t;
                s += t * t;
            }
            ss[mt][reg] = s;
        }
    }
    #pragma unroll
    for (int mt = 0; mt < 4; mt++)
        #pragma unroll
        for (int reg = 0; reg < 4; reg++) {
            float s = ss[mt][reg];
            s += __shfl_xor(s, 1, 64);
            s += __shfl_xor(s, 2, 64);
            s += __shfl_xor(s, 4, 64);
            s += __shfl_xor(s, 8, 64);
            ss[mt][reg] = s;
        }
    if (r == 0) {
        #pragma unroll
        for (int mt = 0; mt < 4; mt++)
            #pragma unroll
            for (int reg = 0; reg < 4; reg++)
                red[wave * 64 + mt * 16 + q * 4 + reg] = ss[mt][reg];
    }
    __syncthreads();
    if (tid < 64) {
        float s = 0.f;
        #pragma unroll
        for (int w = 0; w < 8; w++) s += red[w * 64 + tid];
        invn[tid] = 1.0f / fmaxf(sqrtf(s), 1e-12f);
    }
    __syncthreads();

    #pragma unroll
    for (int mt = 0; mt < 4; mt++) {
        #pragma unroll
        for (int reg = 0; reg < 4; reg++) {
            int m = mt * 16 + q * 4 + reg;
            int gm = m0 + m;
            if (gm < M) {
                float inv = invn[m];
                #pragma unroll
                for (int nt = 0; nt < 4; nt++) {
                    int col = wave * 64 + nt * 16 + r;
                    size_t idx = ((size_t)gm << 9) + col;
                    outp[idx] = f2bf((acc[mt][nt][reg] * inv + bf2f(xb[idx])) * 0.5f);
                }
            }
        }
    }
}

// ---------- final projection: p[i,0:2] = x3[i,:] @ Wf (x3 bf16) ----------
__global__ void proj_kernel(const unsigned short* __restrict__ x3, const float* __restrict__ Wf,
                            float* __restrict__ p, int M) {
    __shared__ float w0[512], w1[512];
    int tid = threadIdx.x;
    for (int j = tid; j < 512; j += 256) { w0[j] = Wf[j * 2]; w1[j] = Wf[j * 2 + 1]; }
    __syncthreads();
    int row = blockIdx.x * 4 + (tid >> 6);
    if (row >= M) return;
    int lane = tid & 63;
    US8 v = *(const US8*)(x3 + ((size_t)row << 9) + lane * 8);
    int j0 = lane * 8;
    float s0 = 0.f, s1 = 0.f;
    #pragma unroll
    for (int t = 0; t < 8; t++) {
        float a = bf2f(v.v[t]);
        s0 += a * w0[j0 + t];
        s1 += a * w1[j0 + t];
    }
    #pragma unroll
    for (int off = 32; off > 0; off >>= 1) {
        s0 += __shfl_xor(s0, off, 64);
        s1 += __shfl_xor(s1, off, 64);
    }
    if (lane == 0) { p[row * 2] = s0; p[row * 2 + 1] = s1; }
}

__global__ void final_self_kernel(const float* __restrict__ p, const float* __restrict__ dinv,
                                  float* pa, int M) {
    int i = blockIdx.x * 256 + threadIdx.x;
    if (i < M) {
        float d = dinv[i]; float s = d * d;
        pa[i * 2] = s * p[i * 2];
        pa[i * 2 + 1] = s * p[i * 2 + 1];
    }
}
__global__ void final_edge_kernel(const float* __restrict__ p, const int* __restrict__ ei,
                                  const float* __restrict__ ew, const float* __restrict__ dinv,
                                  float* pa, int E) {
    int e = blockIdx.x * 256 + threadIdx.x;
    if (e < E) {
        int r = ei[e], c = ei[E + e];
        float coef = dinv[r] * ew[e] * dinv[c];
        atomicAdd(&pa[c * 2], coef * p[r * 2]);
        atomicAdd(&pa[c * 2 + 1], coef * p[r * 2 + 1]);
    }
}
__global__ void lsm_kernel(const float* __restrict__ pa, const float* __restrict__ bfv,
                           float* __restrict__ logp, int M) {
    int i = blockIdx.x * 256 + threadIdx.x;
    if (i < M) {
        float a = pa[i * 2] + bfv[0], b = pa[i * 2 + 1] + bfv[1];
        float m = fmaxf(a, b);
        float lse = m + logf(expf(a - m) + expf(b - m));
        logp[i * 2] = a - lse;
        logp[i * 2 + 1] = b - lse;
    }
}
__global__ void pred_kernel(const float* __restrict__ logp, const int* __restrict__ pe,
                            float* __restrict__ out, int P) {
    int i = blockIdx.x * 256 + threadIdx.x;
    if (i < P) {
        int u = pe[i], v = pe[P + i];
        out[i * 2]     = -(logp[u * 2] * logp[v * 2]);
        out[i * 2 + 1] = -(logp[u * 2 + 1] * logp[v * 2 + 1]);
    }
}

// ---------- launcher ----------
extern "C" void kernel_launch(void* const* d_in, const int* in_sizes, int n_in,
                              void* d_out, int out_size, void* d_ws, size_t ws_size,
                              hipStream_t stream) {
    const float* x   = (const float*)d_in[0];
    const int*   ei  = (const int*)d_in[1];
    const float* ew  = (const float*)d_in[2];
    const int*   pe  = (const int*)d_in[3];
    const float* W1  = (const float*)d_in[4];
    const float* b1  = (const float*)d_in[5];
    const float* W2  = (const float*)d_in[6];
    const float* b2  = (const float*)d_in[7];
    const float* Wf  = (const float*)d_in[8];
    const float* bfv = (const float*)d_in[9];
    float* out = (float*)d_out;

    const int M = in_sizes[0] / 512;
    const int E = in_sizes[2];
    const int P = in_sizes[3] / 2;
    const int NB = (M + 255) / 256;       // scan chunks (<=512 required)
    const int MB64 = (M + 63) / 64;       // fused-layer blocks

    char* ws = (char*)d_ws;
    size_t off = 0;
    auto alloc = [&](size_t bytes) { void* q = ws + off; off += (bytes + 255) & ~(size_t)255; return q; };
    float* deg    = (float*)alloc((size_t)M * 4);
    float* dinv   = (float*)alloc((size_t)M * 4);
    int*   cnt    = (int*)alloc((size_t)M * 4);
    int*   cursor = (int*)alloc((size_t)M * 4);
    int*   rowptr = (int*)alloc((size_t)(M + 1) * 4);
    int*   partial= (int*)alloc((size_t)NB * 4);
    int*   srcidx = (int*)alloc((size_t)E * 4);
    float* cf     = (float*)alloc((size_t)E * 4);
    unsigned short* xb  = (unsigned short*)alloc((size_t)M * 512 * 2);     // x in bf16
    unsigned short* x2b = (unsigned short*)alloc((size_t)M * 512 * 2);     // x2 bf16
    unsigned short* x3b = (unsigned short*)alloc((size_t)M * 512 * 2);     // x3 bf16
    unsigned short* BT1 = (unsigned short*)alloc(512 * 512 * 2);
    unsigned short* BT2 = (unsigned short*)alloc(512 * 512 * 2);
    float* p    = (float*)alloc((size_t)M * 2 * 4);
    float* pa   = (float*)alloc((size_t)M * 2 * 4);
    float* logp = (float*)alloc((size_t)M * 2 * 4);

    const int nthr = 256;

    // ---- x -> bf16, degrees + CSR build (shared by all three convs) ----
    cvt_bf16_kernel<<<(M * 64 + 255) / 256, nthr, 0, stream>>>(x, xb, M * 64);
    init_kernel<<<NB, nthr, 0, stream>>>(deg, cnt, cursor, M);
    deg_cnt_kernel<<<(E + 255) / 256, nthr, 0, stream>>>(ei, ew, deg, cnt, E);
    dinv_kernel<<<NB, nthr, 0, stream>>>(deg, dinv, M);
    chunk_sum_kernel<<<NB, nthr, 0, stream>>>(cnt, partial, M);
    scan_partial_kernel<<<1, 512, 0, stream>>>(partial, NB);
    rowptr_kernel<<<NB, nthr, 0, stream>>>(cnt, partial, rowptr, M, E);
    csr_fill_kernel<<<(E + 255) / 256, nthr, 0, stream>>>(ei, ew, dinv, rowptr, cursor, srcidx, cf, E);
    transpose_cvt_kernel<<<1024, nthr, 0, stream>>>(W1, BT1);
    transpose_cvt_kernel<<<1024, nthr, 0, stream>>>(W2, BT2);

    // ---- layer 1: x2 = epi( (A_norm x) W1 + b1, x ) ----
    fused_layer_kernel<<<MB64, 512, 0, stream>>>(xb, rowptr, srcidx, cf, dinv, BT1, b1, x2b, M);

    // ---- layer 2: x3 = epi( (A_norm x2) W2 + b2, x2 ) ----
    fused_layer_kernel<<<MB64, 512, 0, stream>>>(x2b, rowptr, srcidx, cf, dinv, BT2, b2, x3b, M);

    // ---- final conv + log_softmax + predictor ----
    proj_kernel<<<(M + 3) / 4, nthr, 0, stream>>>(x3b, Wf, p, M);
    final_self_kernel<<<NB, nthr, 0, stream>>>(p, dinv, pa, M);
    final_edge_kernel<<<(E + 255) / 256, nthr, 0, stream>>>(p, ei, ew, dinv, pa, E);
    lsm_kernel<<<NB, nthr, 0, stream>>>(pa, bfv, logp, M);
    pred_kernel<<<(P + 255) / 256, nthr, 0, stream>>>(logp, pe, out, P);
}

// Round 10
// 771.725 us; speedup vs baseline: 1.0965x; 1.0965x over previous
//
#include <hip/hip_runtime.h>
#include <hip/hip_bf16.h>
#include <math.h>

// ---------- types ----------
typedef __bf16 bf16x8 __attribute__((ext_vector_type(8)));
typedef float f32x4 __attribute__((ext_vector_type(4)));
struct __align__(16) US8 { unsigned short v[8]; };

typedef __attribute__((address_space(1))) const unsigned short GUS;
typedef __attribute__((address_space(3))) unsigned short LUS;
static __device__ __forceinline__ void gload16(const unsigned short* g, unsigned short* l) {
    // stages 16B per lane: LDS dest = wave-uniform base + lane*16
    __builtin_amdgcn_global_load_lds((GUS*)g, (LUS*)l, 16, 0, 0);
}

static __device__ __forceinline__ unsigned short f2bf(float f) {
    unsigned int u = __float_as_uint(f);
    unsigned int r = (u + 0x7fffu + ((u >> 16) & 1u)) >> 16;  // RNE
    return (unsigned short)r;
}
static __device__ __forceinline__ float bf2f(unsigned short u) {
    return __uint_as_float(((unsigned int)u) << 16);
}

// ---------- fp32 -> bf16 bulk convert (8 elems/thread) ----------
__global__ void cvt_bf16_kernel(const float* __restrict__ in, unsigned short* __restrict__ outb,
                                int total8) {
    int i = blockIdx.x * 256 + threadIdx.x;
    if (i < total8) {
        const float4* p = (const float4*)(in + (size_t)i * 8);
        float4 a = p[0], b = p[1];
        US8 o;
        o.v[0] = f2bf(a.x); o.v[1] = f2bf(a.y); o.v[2] = f2bf(a.z); o.v[3] = f2bf(a.w);
        o.v[4] = f2bf(b.x); o.v[5] = f2bf(b.y); o.v[6] = f2bf(b.z); o.v[7] = f2bf(b.w);
        *(US8*)(outb + (size_t)i * 8) = o;
    }
}

// ---------- init: deg=1 (self-loop), cnt=0, cursor=0 ----------
__global__ void init_kernel(float* deg, int* cnt, int* cursor, int M) {
    int i = blockIdx.x * 256 + threadIdx.x;
    if (i < M) { deg[i] = 1.0f; cnt[i] = 0; cursor[i] = 0; }
}
// ---------- per-edge: degree accumulate + in-degree count ----------
__global__ void deg_cnt_kernel(const int* __restrict__ ei, const float* __restrict__ ew,
                               float* deg, int* cnt, int E) {
    int e = blockIdx.x * 256 + threadIdx.x;
    if (e < E) {
        int c = ei[E + e];
        atomicAdd(&deg[c], ew[e]);
        atomicAdd(&cnt[c], 1);
    }
}
__global__ void dinv_kernel(const float* __restrict__ deg, float* dinv, int M) {
    int i = blockIdx.x * 256 + threadIdx.x;
    if (i < M) dinv[i] = rsqrtf(deg[i]);  // deg >= 1 always
}

// ---------- CSR build: chunk sums -> scan partials -> rowptr -> fill ----------
__global__ void chunk_sum_kernel(const int* __restrict__ cnt, int* partial, int M) {
    __shared__ int sd[256];
    int t = threadIdx.x;
    int i = blockIdx.x * 256 + t;
    sd[t] = (i < M) ? cnt[i] : 0;
    __syncthreads();
    for (int s = 128; s > 0; s >>= 1) {
        if (t < s) sd[t] += sd[t + s];
        __syncthreads();
    }
    if (t == 0) partial[blockIdx.x] = sd[0];
}
// single block, 512 threads, NB <= 512; partial becomes EXCLUSIVE scan
__global__ void scan_partial_kernel(int* partial, int NB) {
    __shared__ int sd[512];
    int t = threadIdx.x;
    int v = (t < NB) ? partial[t] : 0;
    sd[t] = v;
    __syncthreads();
    for (int o = 1; o < 512; o <<= 1) {
        int add = (t >= o) ? sd[t - o] : 0;
        __syncthreads();
        sd[t] += add;
        __syncthreads();
    }
    if (t < NB) partial[t] = sd[t] - v;  // exclusive
}
__global__ void rowptr_kernel(const int* __restrict__ cnt, const int* __restrict__ partial,
                              int* rowptr, int M, int E) {
    __shared__ int sd[256];
    int t = threadIdx.x;
    int i = blockIdx.x * 256 + t;
    int v = (i < M) ? cnt[i] : 0;
    sd[t] = v;
    __syncthreads();
    for (int o = 1; o < 256; o <<= 1) {
        int add = (t >= o) ? sd[t - o] : 0;
        __syncthreads();
        sd[t] += add;
        __syncthreads();
    }
    if (i < M) rowptr[i] = partial[blockIdx.x] + sd[t] - v;  // exclusive overall
    if (i == M - 1) rowptr[M] = E;
}
__global__ void csr_fill_kernel(const int* __restrict__ ei, const float* __restrict__ ew,
                                const float* __restrict__ dinv, const int* __restrict__ rowptr,
                                int* cursor, int* src, float* cf, int E) {
    int e = blockIdx.x * 256 + threadIdx.x;
    if (e < E) {
        int r = ei[e], c = ei[E + e];
        int k = atomicAdd(&cursor[c], 1);
        int pos = rowptr[c] + k;
        src[pos] = r;
        cf[pos] = dinv[r] * ew[e] * dinv[c];
    }
}

// ---------- aggregation (gather), bf16 in / bf16 out, fp32 math ----------
__global__ void agg_gather_kernel(const unsigned short* __restrict__ xin, const int* __restrict__ rowptr,
                                  const int* __restrict__ src, const float* __restrict__ cf,
                                  const float* __restrict__ dinv,
                                  unsigned short* __restrict__ abf, int M) {
    int row = blockIdx.x * 4 + (threadIdx.x >> 6);
    if (row >= M) return;
    int lane = threadIdx.x & 63;
    US8 v = *(const US8*)(xin + ((size_t)row << 9) + lane * 8);
    float d = dinv[row];
    float s = d * d;
    float a[8];
    #pragma unroll
    for (int t = 0; t < 8; t++) a[t] = s * bf2f(v.v[t]);
    int beg = rowptr[row], end = rowptr[row + 1];
    for (int j = beg; j < end; j++) {
        int r = src[j];
        float coef = cf[j];
        US8 u = *(const US8*)(xin + ((size_t)r << 9) + lane * 8);
        #pragma unroll
        for (int t = 0; t < 8; t++) a[t] += coef * bf2f(u.v[t]);
    }
    US8 o;
    #pragma unroll
    for (int t = 0; t < 8; t++) o.v[t] = f2bf(a[t]);
    *(US8*)(abf + ((size_t)row << 9) + lane * 8) = o;
}

// ---------- W1,W2 (512x512 row-major k,n) -> BT1,BT2 bf16 (n,k), one launch ----------
__global__ void transpose_cvt2_kernel(const float* __restrict__ W1, const float* __restrict__ W2,
                                      unsigned short* __restrict__ BT1, unsigned short* __restrict__ BT2) {
    int idx = blockIdx.x * 256 + threadIdx.x;  // 2 * 512*512
    const float* W = (idx < 262144) ? W1 : W2;
    unsigned short* BT = (idx < 262144) ? BT1 : BT2;
    int i = idx & 262143;
    int n = i >> 9, k = i & 511;
    BT[i] = f2bf(W[k * 512 + n]);
}

// ---------- fused GEMM + epilogue (R7 structure) + optional fused projection ----------
// Block: 512 threads = 8 waves. BM=64 rows x BN=512 (full row -> fused norm).
// K-loop: BK=32, 16 iters; stage A(64x32)+B(512x32) via global_load_lds(16B),
// barrier, 16 MFMAs/wave from LDS, barrier. Chunk-col swizzle kc^=((row+row>>2)&3).
// Epilogue: t = relu(C+bias); rownorm; out = bf16((t/||t|| + xin)*0.5).
// If Wf != nullptr: also p[row,0:2] = out_row . Wf (reuses cross-wave reduction).
__global__ __launch_bounds__(512, 4) void gemm_epi_kernel(
    const unsigned short* __restrict__ A,   // [Mpad,512] bf16 aggregated
    const unsigned short* __restrict__ BT,  // [512,512] bf16, n-major
    const float* __restrict__ bias,         // [512]
    const unsigned short* __restrict__ xin, // [M,512] bf16 residual input
    unsigned short* __restrict__ outp,      // [M,512] bf16
    const float* __restrict__ Wf,           // [512,2] or nullptr
    float* __restrict__ p,                  // [M,2] or nullptr
    int M) {
    __shared__ __align__(16) unsigned short As[64 * 32];    // 4 KB
    __shared__ __align__(16) unsigned short Bs[512 * 32];   // 32 KB
    __shared__ float red[8 * 64];
    __shared__ float invn[64];
    __shared__ float pr0[8 * 64];
    __shared__ float pr1[8 * 64];

    const int tid  = threadIdx.x;
    const int m0   = blockIdx.x * 64;
    const int wave = tid >> 6;
    const int lane = tid & 63;
    const int q    = lane >> 4;   // 0..3
    const int r    = lane & 15;
    const bool doproj = (Wf != nullptr);

    f32x4 acc[4][4];
    #pragma unroll
    for (int mt = 0; mt < 4; mt++)
        #pragma unroll
        for (int nt = 0; nt < 4; nt++) acc[mt][nt] = (f32x4){0.f, 0.f, 0.f, 0.f};

    const int fr  = (r + (r >> 2)) & 3;   // swizzle term (per-lane constant)
    const int kcp = q ^ fr;               // LDS chunk column for fragments

    for (int ks = 0; ks < 16; ks++) {
        const int k0 = ks * 32;
        // ---- stage: chunks 0..255 = A (row=c>>2, kc'=c&3), 256..2303 = B ----
        #pragma unroll
        for (int j = 0; j < 4; j++) {
            int c0 = j * 512 + wave * 64;   // wave-uniform chunk base
            int c  = c0 + lane;
            if (c0 < 256) {
                int row = c >> 2, kl = c & 3;
                int kc = kl ^ ((row + (row >> 2)) & 3);
                gload16(A + (((size_t)(m0 + row)) << 9) + k0 + kc * 8, As + c0 * 8);
            } else {
                int cb = c - 256, cb0 = c0 - 256;
                int n = cb >> 2, kl = cb & 3;
                int kc = kl ^ ((n + (n >> 2)) & 3);
                gload16(BT + (((size_t)n) << 9) + k0 + kc * 8, Bs + cb0 * 8);
            }
        }
        if (wave < 4) {  // chunks 2048..2303 (B 1792..2047)
            int cb0 = 1792 + wave * 64;
            int cb = cb0 + lane;
            int n = cb >> 2, kl = cb & 3;
            int kc = kl ^ ((n + (n >> 2)) & 3);
            gload16(BT + (((size_t)n) << 9) + k0 + kc * 8, Bs + cb0 * 8);
        }
        __syncthreads();

        // ---- compute ----
        bf16x8 af[4];
        #pragma unroll
        for (int mt = 0; mt < 4; mt++)
            af[mt] = __builtin_bit_cast(bf16x8,
                *(const US8*)&As[((mt * 16 + r) << 5) + kcp * 8]);
        #pragma unroll
        for (int nt = 0; nt < 4; nt++) {
            bf16x8 bfr = __builtin_bit_cast(bf16x8,
                *(const US8*)&Bs[((wave * 64 + nt * 16 + r) << 5) + kcp * 8]);
            #pragma unroll
            for (int mt = 0; mt < 4; mt++)
                acc[mt][nt] = __builtin_amdgcn_mfma_f32_16x16x32_bf16(af[mt], bfr, acc[mt][nt], 0, 0, 0);
        }
        __syncthreads();
    }

    // ---- epilogue: bias + relu (in place), per-row sum of squares ----
    float bs[4];
    #pragma unroll
    for (int nt = 0; nt < 4; nt++) bs[nt] = bias[wave * 64 + nt * 16 + r];

    float wf0[4], wf1[4];
    if (doproj) {
        #pragma unroll
        for (int nt = 0; nt < 4; nt++) {
            int col = wave * 64 + nt * 16 + r;
            wf0[nt] = Wf[col * 2];
            wf1[nt] = Wf[col * 2 + 1];
        }
    }

    float ss[4][4];
    #pragma unroll
    for (int mt = 0; mt < 4; mt++) {
        #pragma unroll
        for (int reg = 0; reg < 4; reg++) {
            float s = 0.f;
            #pragma unroll
            for (int nt = 0; nt < 4; nt++) {
                float t = fmaxf(acc[mt][nt][reg] + bs[nt], 0.f);
                acc[mt][nt][reg] = t;
                s += t * t;
            }
            ss[mt][reg] = s;
        }
    }
    // reduce over the 16 lanes of each quad (r dimension)
    #pragma unroll
    for (int mt = 0; mt < 4; mt++)
        #pragma unroll
        for (int reg = 0; reg < 4; reg++) {
            float s = ss[mt][reg];
            s += __shfl_xor(s, 1, 64);
            s += __shfl_xor(s, 2, 64);
            s += __shfl_xor(s, 4, 64);
            s += __shfl_xor(s, 8, 64);
            ss[mt][reg] = s;
        }
    if (r == 0) {
        #pragma unroll
        for (int mt = 0; mt < 4; mt++)
            #pragma unroll
            for (int reg = 0; reg < 4; reg++)
                red[wave * 64 + mt * 16 + q * 4 + reg] = ss[mt][reg];
    }
    __syncthreads();
    if (tid < 64) {
        float s = 0.f;
        #pragma unroll
        for (int w = 0; w < 8; w++) s += red[w * 64 + tid];
        invn[tid] = 1.0f / fmaxf(sqrtf(s), 1e-12f);
    }
    __syncthreads();

    // ---- normalize + residual + store (bf16); optional projection partials ----
    #pragma unroll
    for (int mt = 0; mt < 4; mt++) {
        #pragma unroll
        for (int reg = 0; reg < 4; reg++) {
            int m = mt * 16 + q * 4 + reg;
            int gm = m0 + m;
            float inv = invn[m];
            float s0 = 0.f, s1 = 0.f;
            if (gm < M) {
                #pragma unroll
                for (int nt = 0; nt < 4; nt++) {
                    int col = wave * 64 + nt * 16 + r;
                    size_t idx = ((size_t)gm << 9) + col;
                    unsigned short ob = f2bf((acc[mt][nt][reg] * inv + bf2f(xin[idx])) * 0.5f);
                    outp[idx] = ob;
                    if (doproj) {
                        float vv = bf2f(ob);   // bit-exact with stored value
                        s0 += vv * wf0[nt];
                        s1 += vv * wf1[nt];
                    }
                }
            }
            if (doproj) {
                s0 += __shfl_xor(s0, 1, 64); s1 += __shfl_xor(s1, 1, 64);
                s0 += __shfl_xor(s0, 2, 64); s1 += __shfl_xor(s1, 2, 64);
                s0 += __shfl_xor(s0, 4, 64); s1 += __shfl_xor(s1, 4, 64);
                s0 += __shfl_xor(s0, 8, 64); s1 += __shfl_xor(s1, 8, 64);
                if (r == 0) { pr0[wave * 64 + m] = s0; pr1[wave * 64 + m] = s1; }
            }
        }
    }
    if (doproj) {
        __syncthreads();
        if (tid < 64) {
            int gm = m0 + tid;
            if (gm < M) {
                float t0 = 0.f, t1 = 0.f;
                #pragma unroll
                for (int w = 0; w < 8; w++) { t0 += pr0[w * 64 + tid]; t1 += pr1[w * 64 + tid]; }
                p[gm * 2] = t0; p[gm * 2 + 1] = t1;
            }
        }
    }
}

__global__ void final_self_kernel(const float* __restrict__ p, const float* __restrict__ dinv,
                                  float* pa, int M) {
    int i = blockIdx.x * 256 + threadIdx.x;
    if (i < M) {
        float d = dinv[i]; float s = d * d;
        pa[i * 2] = s * p[i * 2];
        pa[i * 2 + 1] = s * p[i * 2 + 1];
    }
}
__global__ void final_edge_kernel(const float* __restrict__ p, const int* __restrict__ ei,
                                  const float* __restrict__ ew, const float* __restrict__ dinv,
                                  float* pa, int E) {
    int e = blockIdx.x * 256 + threadIdx.x;
    if (e < E) {
        int r = ei[e], c = ei[E + e];
        float coef = dinv[r] * ew[e] * dinv[c];
        atomicAdd(&pa[c * 2], coef * p[r * 2]);
        atomicAdd(&pa[c * 2 + 1], coef * p[r * 2 + 1]);
    }
}
__global__ void lsm_kernel(const float* __restrict__ pa, const float* __restrict__ bfv,
                           float* __restrict__ logp, int M) {
    int i = blockIdx.x * 256 + threadIdx.x;
    if (i < M) {
        float a = pa[i * 2] + bfv[0], b = pa[i * 2 + 1] + bfv[1];
        float m = fmaxf(a, b);
        float lse = m + logf(expf(a - m) + expf(b - m));
        logp[i * 2] = a - lse;
        logp[i * 2 + 1] = b - lse;
    }
}
__global__ void pred_kernel(const float* __restrict__ logp, const int* __restrict__ pe,
                            float* __restrict__ out, int P) {
    int i = blockIdx.x * 256 + threadIdx.x;
    if (i < P) {
        int u = pe[i], v = pe[P + i];
        out[i * 2]     = -(logp[u * 2] * logp[v * 2]);
        out[i * 2 + 1] = -(logp[u * 2 + 1] * logp[v * 2 + 1]);
    }
}

// ---------- launcher ----------
extern "C" void kernel_launch(void* const* d_in, const int* in_sizes, int n_in,
                              void* d_out, int out_size, void* d_ws, size_t ws_size,
                              hipStream_t stream) {
    const float* x   = (const float*)d_in[0];
    const int*   ei  = (const int*)d_in[1];
    const float* ew  = (const float*)d_in[2];
    const int*   pe  = (const int*)d_in[3];
    const float* W1  = (const float*)d_in[4];
    const float* b1  = (const float*)d_in[5];
    const float* W2  = (const float*)d_in[6];
    const float* b2  = (const float*)d_in[7];
    const float* Wf  = (const float*)d_in[8];
    const float* bfv = (const float*)d_in[9];
    float* out = (float*)d_out;

    const int M = in_sizes[0] / 512;
    const int E = in_sizes[2];
    const int P = in_sizes[3] / 2;
    const int NB = (M + 255) / 256;       // scan chunks (<=512 required)
    const int MB64 = (M + 63) / 64;       // gemm blocks
    const int Mpad = MB64 * 64;

    char* ws = (char*)d_ws;
    size_t off = 0;
    auto alloc = [&](size_t bytes) { void* q = ws + off; off += (bytes + 255) & ~(size_t)255; return q; };
    float* deg    = (float*)alloc((size_t)M * 4);
    float* dinv   = (float*)alloc((size_t)M * 4);
    int*   cnt    = (int*)alloc((size_t)M * 4);
    int*   cursor = (int*)alloc((size_t)M * 4);
    int*   rowptr = (int*)alloc((size_t)(M + 1) * 4);
    int*   partial= (int*)alloc((size_t)NB * 4);
    int*   srcidx = (int*)alloc((size_t)E * 4);
    float* cf     = (float*)alloc((size_t)E * 4);
    unsigned short* xb  = (unsigned short*)alloc((size_t)M * 512 * 2);     // x in bf16
    unsigned short* x2b = (unsigned short*)alloc((size_t)M * 512 * 2);     // x2 bf16
    unsigned short* x3b = (unsigned short*)alloc((size_t)M * 512 * 2);     // x3 bf16
    unsigned short* abf = (unsigned short*)alloc((size_t)Mpad * 512 * 2);  // aggregated (GEMM A), padded
    unsigned short* BT1 = (unsigned short*)alloc(512 * 512 * 2);
    unsigned short* BT2 = (unsigned short*)alloc(512 * 512 * 2);
    float* p    = (float*)alloc((size_t)M * 2 * 4);
    float* pa   = (float*)alloc((size_t)M * 2 * 4);
    float* logp = (float*)alloc((size_t)M * 2 * 4);

    const int nthr = 256;

    // ---- x -> bf16, degrees + CSR build (shared by all three convs) ----
    cvt_bf16_kernel<<<(M * 64 + 255) / 256, nthr, 0, stream>>>(x, xb, M * 64);
    init_kernel<<<NB, nthr, 0, stream>>>(deg, cnt, cursor, M);
    deg_cnt_kernel<<<(E + 255) / 256, nthr, 0, stream>>>(ei, ew, deg, cnt, E);
    dinv_kernel<<<NB, nthr, 0, stream>>>(deg, dinv, M);
    chunk_sum_kernel<<<NB, nthr, 0, stream>>>(cnt, partial, M);
    scan_partial_kernel<<<1, 512, 0, stream>>>(partial, NB);
    rowptr_kernel<<<NB, nthr, 0, stream>>>(cnt, partial, rowptr, M, E);
    csr_fill_kernel<<<(E + 255) / 256, nthr, 0, stream>>>(ei, ew, dinv, rowptr, cursor, srcidx, cf, E);
    transpose_cvt2_kernel<<<2048, nthr, 0, stream>>>(W1, W2, BT1, BT2);

    // ---- layer 1: x2 = epi( (A_norm x) W1 + b1, x ) ----
    agg_gather_kernel<<<(M + 3) / 4, nthr, 0, stream>>>(xb, rowptr, srcidx, cf, dinv, abf, M);
    gemm_epi_kernel<<<MB64, 512, 0, stream>>>(abf, BT1, b1, xb, x2b, nullptr, nullptr, M);

    // ---- layer 2: x3 = epi( (A_norm x2) W2 + b2, x2 ), fused p = x3 @ Wf ----
    agg_gather_kernel<<<(M + 3) / 4, nthr, 0, stream>>>(x2b, rowptr, srcidx, cf, dinv, abf, M);
    gemm_epi_kernel<<<MB64, 512, 0, stream>>>(abf, BT2, b2, x2b, x3b, Wf, p, M);

    // ---- final conv + log_softmax + predictor ----
    final_self_kernel<<<NB, nthr, 0, stream>>>(p, dinv, pa, M);
    final_edge_kernel<<<(E + 255) / 256, nthr, 0, stream>>>(p, ei, ew, dinv, pa, E);
    lsm_kernel<<<NB, nthr, 0, stream>>>(pa, bfv, logp, M);
    pred_kernel<<<(P + 255) / 256, nthr, 0, stream>>>(logp, pe, out, P);
}